// Round 13
// baseline (281.187 us; speedup 1.0000x reference)
//
#include <hip/hip_runtime.h>
#include <math.h>

#define NN 50000
#define NE 800000
#define EBLOCKS (NE / 32)          // 25000 edge blocks (32 edges, 256 thr)
#define WBLOCKS ((NN + 63) / 64)   // 782 world blocks

typedef float     f32x4  __attribute__((ext_vector_type(4)));
typedef __bf16    bf16x8 __attribute__((ext_vector_type(8)));
typedef _Float16  f16x2  __attribute__((ext_vector_type(2)));
typedef _Float16  f16x8  __attribute__((ext_vector_type(8)));

// ws layout: [0,256) m_agg_w (64 f32). [256,...) bf16 weight fragments.
#define WE1F_OFF 0        // 5120: We1||Wg1  (kc<5, ct<16)  K 136->160
#define WE2F_OFF 5120     // 1024: We2       (kc<4, ct<4)
#define WN1F_OFF 6144     // 2048: Wn1       (kc<4, ct<8)
#define WN2F_OFF 8192     // 1024: Wn2       (kc<4, ct<4)
#define WW1F_OFF 9216     // 1536: Ww1       (kc<3, ct<8)   K 67->96
#define WW2F_OFF 10752    // 1024: Ww2       (kc<4, ct<4)
#define NCHUNKS  11776

// d_out row n (256 B): first 128 B = f16[64] m_agg accumulator (atomic
// target, zeroed by prep); second 128 B = bf16[64] z_h row n (gather table,
// written by prep). node_kernel block n reads both halves of its rows then
// overwrites them -> race-free, zero extra workspace.

__device__ inline bf16x8 pack8(float4 a, float4 b) {
    bf16x8 r;
    r[0] = (__bf16)a.x; r[1] = (__bf16)a.y; r[2] = (__bf16)a.z; r[3] = (__bf16)a.w;
    r[4] = (__bf16)b.x; r[5] = (__bf16)b.y; r[6] = (__bf16)b.z; r[7] = (__bf16)b.w;
    return r;
}

// packed 2x f16 atomic fadd (global_atomic_pk_add_f16, gfx90a+).
__device__ inline void pk_atomic_add_f16(void* addr, f16x2 v) {
#if __has_builtin(__builtin_amdgcn_global_atomic_fadd_v2f16)
    __builtin_amdgcn_global_atomic_fadd_v2f16((f16x2*)addr, v);
#else
    asm volatile("global_atomic_pk_add_f16 %0, %1, off"
                 :: "v"(addr), "v"(v) : "memory");
#endif
}

// ------- single prep kernel: weight fragments + z-bf16 table + zeroing -----
__global__ __launch_bounds__(256) void prep(
    const float* __restrict__ We1, const float* __restrict__ Wg1,
    const float* __restrict__ We2, const float* __restrict__ Wn1,
    const float* __restrict__ Wn2, const float* __restrict__ Ww1,
    const float* __restrict__ Ww2, bf16x8* __restrict__ wsF,
    const float* __restrict__ z, float* __restrict__ db,
    float* __restrict__ m_agg_w)
{
    const int c = blockIdx.x * 256 + threadIdx.x;

    if (c < 64) m_agg_w[c] = 0.f;

    if (c < NN * 8) {      // z-table (2nd half) + zero f16 acc (1st half)
        int node = c >> 3, q = c & 7;
        const float4* s = (const float4*)(z + (long)node * 64) + q * 2;
        float4 a = s[0], b = s[1];
        *(bf16x8*)((char*)db + (long)node * 256 + 128 + q * 16) = pack8(a, b);
        float4 zz = {0.f, 0.f, 0.f, 0.f};
        *(float4*)((char*)db + (long)node * 256 + q * 16) = zz;
    }

    if (c >= NCHUNKS) return;
    const int lane = c & 63, l16 = lane & 15, row8 = ((lane >> 4) & 3) * 8;
    bf16x8 p;
    if (c < WE2F_OFF) {                       // We1 || Wg1, pad K 136->160
        int ct = (c >> 6) & 15, kc = c >> 10;
        int col = ct * 16 + l16;
        const float* src = (col < 128) ? (We1 + col) : (Wg1 + (col - 128));
#pragma unroll
        for (int i = 0; i < 8; i++) {
            int r = kc * 32 + row8 + i;
            p[i] = (__bf16)((r < 136) ? src[(size_t)r * 128] : 0.f);
        }
    } else if (c < WN1F_OFF) {
        int cc = c - WE2F_OFF; int ct = (cc >> 6) & 3, kc = cc >> 8;
        int col = ct * 16 + l16;
#pragma unroll
        for (int i = 0; i < 8; i++)
            p[i] = (__bf16)We2[(size_t)(kc * 32 + row8 + i) * 64 + col];
    } else if (c < WN2F_OFF) {
        int cc = c - WN1F_OFF; int ct = (cc >> 6) & 7, kc = cc >> 9;
        int col = ct * 16 + l16;
#pragma unroll
        for (int i = 0; i < 8; i++)
            p[i] = (__bf16)Wn1[(size_t)(kc * 32 + row8 + i) * 128 + col];
    } else if (c < WW1F_OFF) {
        int cc = c - WN2F_OFF; int ct = (cc >> 6) & 3, kc = cc >> 8;
        int col = ct * 16 + l16;
#pragma unroll
        for (int i = 0; i < 8; i++)
            p[i] = (__bf16)Wn2[(size_t)(kc * 32 + row8 + i) * 64 + col];
    } else if (c < WW2F_OFF) {                // Ww1, pad K 67->96
        int cc = c - WW1F_OFF; int ct = (cc >> 6) & 7, kc = cc >> 9;
        int col = ct * 16 + l16;
#pragma unroll
        for (int i = 0; i < 8; i++) {
            int r = kc * 32 + row8 + i;
            p[i] = (__bf16)((r < 67) ? Ww1[(size_t)r * 128 + col] : 0.f);
        }
    } else {
        int cc = c - WW2F_OFF; int ct = (cc >> 6) & 3, kc = cc >> 8;
        int col = ct * 16 + l16;
#pragma unroll
        for (int i = 0; i < 8; i++)
            p[i] = (__bf16)Ww2[(size_t)(kc * 32 + row8 + i) * 64 + col];
    }
    wsF[c] = p;
}

// --------- fused edge + world kernel: blocks [0,EBLOCKS) = edges, rest = world
// Edge path (R13 = R12 + launch_bounds(256,8)): 32 edges/block, 4 waves ->
// up to 8 resident blocks/CU (VGPR 40 <= 64 budget, LDS 17.4 KB x 8 < 160).
union FusedLds {
    bf16x8 XF[1024];                    // world gather 12 tiles / world HF 16 KB
    struct {
        bf16x8   HF[512];               // edge HF 8 KB (aliases dead XF)
        _Float16 M[32 * 68];            // 4.4 KB
    } s;
};

__global__ __launch_bounds__(256, 8) void fused_kernel(
    const float* __restrict__ z_h, const int* __restrict__ ei,
    const bf16x8* __restrict__ We1F, const bf16x8* __restrict__ We2F,
    const float* __restrict__ be1, const float* __restrict__ be2,
    const float* __restrict__ bg1, const float* __restrict__ Wg2,
    const float* __restrict__ bg2,
    const float* __restrict__ pos_world,
    const bf16x8* __restrict__ Ww1F, const bf16x8* __restrict__ Ww2F,
    const float* __restrict__ bw1, const float* __restrict__ bw2,
    float* __restrict__ magg_rows,     // = d_out; acc first half, z-bf16 second
    float* __restrict__ m_agg_w)
{
    __shared__ FusedLds U;
    __shared__ int   tgt_s[32];
    __shared__ float gred[4][32];

    const int t = threadIdx.x;               // 0..255
    const int lane = t & 63, w = t >> 6;     // w 0..3
    const int quad = lane >> 4, l16 = lane & 15;

    if (blockIdx.x >= EBLOCKS) {
        // ================= world path (256-thread, 64 nodes) ================
        const int n0 = (blockIdx.x - EBLOCKS) * 64;
        {   // gather: 4 threads/node
            int nn = t >> 2, q = t & 3;
            int mt = nn >> 4, l16e = nn & 15;
            int node = n0 + nn; if (node >= NN) node = NN - 1;
            const float4* zr = (const float4*)(z_h + (long)node * 64) + q * 4;
            float4 a0 = zr[0], a1 = zr[1], a2 = zr[2], a3 = zr[3];
            int kcs = q >> 1, qa = (q & 1) * 2;
            U.XF[(kcs * 4 + mt) * 64 + qa * 16 + l16e]       = pack8(a0, a1);
            U.XF[(kcs * 4 + mt) * 64 + (qa + 1) * 16 + l16e] = pack8(a2, a3);
            if (q == 0) {
                bf16x8 f;
#pragma unroll
                for (int i = 0; i < 8; i++) f[i] = (__bf16)0.f;
                f[0] = (__bf16)(a0.x - pos_world[0]);
                f[1] = (__bf16)(a0.y - pos_world[1]);
                f[2] = (__bf16)(a0.z - pos_world[2]);
                U.XF[(8 + mt) * 64 + l16e] = f;
            } else {
                bf16x8 z8;
#pragma unroll
                for (int i = 0; i < 8; i++) z8[i] = (__bf16)0.f;
                U.XF[(8 + mt) * 64 + q * 16 + l16e] = z8;
            }
        }
        __syncthreads();

        f32x4 acc[4][2];
#pragma unroll
        for (int nt2 = 0; nt2 < 2; nt2++) {
            float b = bw1[(w * 2 + nt2) * 16 + l16];
#pragma unroll
            for (int mt = 0; mt < 4; mt++) { f32x4 v = {b, b, b, b}; acc[mt][nt2] = v; }
        }
#pragma unroll
        for (int kc = 0; kc < 3; kc++) {
#pragma unroll
            for (int nt2 = 0; nt2 < 2; nt2++) {
                bf16x8 bfr = Ww1F[(kc * 8 + w * 2 + nt2) * 64 + lane];
#pragma unroll
                for (int mt = 0; mt < 4; mt++)
                    acc[mt][nt2] = __builtin_amdgcn_mfma_f32_16x16x32_bf16(
                        U.XF[(kc * 4 + mt) * 64 + lane], bfr, acc[mt][nt2], 0, 0, 0);
            }
        }
        __syncthreads();

        {   // relu + transpose -> HF (aliases XF base)
            __bf16* HFp = (__bf16*)U.XF;
#pragma unroll
            for (int nt2 = 0; nt2 < 2; nt2++) {
                int cw = (w * 2 + nt2) * 16 + l16;
                int kc2 = cw >> 5, quad2 = (cw >> 3) & 3, ii = cw & 7;
#pragma unroll
                for (int mt = 0; mt < 4; mt++)
#pragma unroll
                    for (int r = 0; r < 4; r++)
                        HFp[(((kc2 * 4 + mt) * 64) + quad2 * 16 + quad * 4 + r) * 8 + ii] =
                            (__bf16)fmaxf(acc[mt][nt2][r], 0.f);
            }
        }
        __syncthreads();

        {   // GEMM2 + masked column-sum (wave w = col-tile, mh loop)
            f32x4 acc2[2][2];
            float b2 = bw2[w * 16 + l16];
#pragma unroll
            for (int mh = 0; mh < 2; mh++)
#pragma unroll
                for (int m = 0; m < 2; m++) { f32x4 v = {b2, b2, b2, b2}; acc2[mh][m] = v; }
#pragma unroll
            for (int kc = 0; kc < 4; kc++) {
                bf16x8 b2f = Ww2F[(kc * 4 + w) * 64 + lane];
#pragma unroll
                for (int mh = 0; mh < 2; mh++)
#pragma unroll
                    for (int m = 0; m < 2; m++)
                        acc2[mh][m] = __builtin_amdgcn_mfma_f32_16x16x32_bf16(
                            U.XF[(kc * 4 + mh * 2 + m) * 64 + lane], b2f, acc2[mh][m], 0, 0, 0);
            }
            float s = 0.f;
#pragma unroll
            for (int mh = 0; mh < 2; mh++)
#pragma unroll
                for (int m = 0; m < 2; m++)
#pragma unroll
                    for (int r = 0; r < 4; r++) {
                        int node = n0 + (mh * 2 + m) * 16 + quad * 4 + r;
                        s += (node < NN) ? acc2[mh][m][r] : 0.f;
                    }
            s += __shfl_xor(s, 16, 64);
            s += __shfl_xor(s, 32, 64);
            if (quad == 0) atomicAdd(m_agg_w + w * 16 + l16, s);
        }
        return;
    }

    // ================= edge path (32 edges/block, bf16 table gather) ========
    const int e0 = blockIdx.x * 32;          // NE % 32 == 0

    {   // ---- gather: 8 threads/edge, thread q loads 16B chunk q of BOTH rows
        const int ee = t >> 3, q = t & 7;    // ee 0..31
        const int mt = ee >> 4, l16e = ee & 15;
        const int eg = e0 + ee;
        const int rs = ei[eg], rt = ei[NE + eg];
        const bf16x8* zs = (const bf16x8*)((const char*)magg_rows + (long)rs * 256 + 128);
        const bf16x8* zt = (const bf16x8*)((const char*)magg_rows + (long)rt * 256 + 128);
        bf16x8 sa = zs[q];                   // src cols q*8 .. q*8+7
        bf16x8 ta = zt[q];                   // tgt cols q*8 .. q*8+7
        const int kcs = q >> 2, qslot = q & 3;
        U.XF[(kcs * 2 + mt) * 64 + qslot * 16 + l16e]       = sa;
        U.XF[((kcs + 2) * 2 + mt) * 64 + qslot * 16 + l16e] = ta;
        if (q == 4) tgt_s[ee] = rt;
        if (q == 0) {        // edge features (cols 128..135) from bf16 chunk 0
            float dx = (float)sa[0] - (float)ta[0];
            float dy = (float)sa[1] - (float)ta[1];
            float dz = (float)sa[2] - (float)ta[2];
            float ax = (float)sa[3], ay = (float)sa[4], az = (float)sa[5];
            float bx = (float)ta[3], by = (float)ta[4], bz = (float)ta[5];
            float cx = ay * bz - az * by;
            float cy = az * bx - ax * bz;
            float cz = ax * by - ay * bx;
            bf16x8 f;
            f[0] = (__bf16)dx; f[1] = (__bf16)dy; f[2] = (__bf16)dz;
            f[3] = (__bf16)(dx * dx + dy * dy + dz * dz);
            f[4] = (__bf16)cx; f[5] = (__bf16)cy; f[6] = (__bf16)cz;
            f[7] = (__bf16)sqrtf(cx * cx + cy * cy + cz * cz);
            U.XF[(8 + mt) * 64 + l16e] = f;
        } else if (q >= 5) { // zero pad (cols 136..159)
            bf16x8 z;
#pragma unroll
            for (int i = 0; i < 8; i++) z[i] = (__bf16)0.f;
            U.XF[(8 + mt) * 64 + (q - 4) * 16 + l16e] = z;
        }
    }
    __syncthreads();                         // B1: XF + tgt_s ready

    // ---- GEMM1: wave owns 4 col-tiles (msg 2w,2w+1; gate 8+2w,8+2w+1) ----
    f32x4 acc[2][4];
#pragma unroll
    for (int nt = 0; nt < 4; nt++) {
        float b = (nt < 2) ? be1[(w * 2 + nt) * 16 + l16]
                           : bg1[(w * 2 + nt - 2) * 16 + l16];
#pragma unroll
        for (int mt = 0; mt < 2; mt++) { f32x4 v = {b, b, b, b}; acc[mt][nt] = v; }
    }
#pragma unroll
    for (int kc = 0; kc < 5; kc++) {
        bf16x8 bf0 = We1F[(kc * 16 + w * 2) * 64 + lane];
        bf16x8 bf1 = We1F[(kc * 16 + w * 2 + 1) * 64 + lane];
        bf16x8 bf2 = We1F[(kc * 16 + 8 + w * 2) * 64 + lane];
        bf16x8 bf3 = We1F[(kc * 16 + 8 + w * 2 + 1) * 64 + lane];
#pragma unroll
        for (int mt = 0; mt < 2; mt++) {
            bf16x8 af = U.XF[(kc * 2 + mt) * 64 + lane];
            acc[mt][0] = __builtin_amdgcn_mfma_f32_16x16x32_bf16(af, bf0, acc[mt][0], 0, 0, 0);
            acc[mt][1] = __builtin_amdgcn_mfma_f32_16x16x32_bf16(af, bf1, acc[mt][1], 0, 0, 0);
            acc[mt][2] = __builtin_amdgcn_mfma_f32_16x16x32_bf16(af, bf2, acc[mt][2], 0, 0, 0);
            acc[mt][3] = __builtin_amdgcn_mfma_f32_16x16x32_bf16(af, bf3, acc[mt][3], 0, 0, 0);
        }
    }
    __syncthreads();                         // B2: XF reads done (HF may overwrite)

    {   // ---- all waves: relu+transpose msg tiles -> HF, gate partials ----
        __bf16* HFp = (__bf16*)U.s.HF;
#pragma unroll
        for (int nt = 0; nt < 2; nt++) {
            int cw = (w * 2 + nt) * 16 + l16;
            int kc2 = cw >> 5, quad2 = (cw >> 3) & 3, ii = cw & 7;
#pragma unroll
            for (int mt = 0; mt < 2; mt++)
#pragma unroll
                for (int r = 0; r < 4; r++)
                    HFp[(((kc2 * 2 + mt) * 64) + quad2 * 16 + quad * 4 + r) * 8 + ii] =
                        (__bf16)fmaxf(acc[mt][nt][r], 0.f);
        }
        float gp[2][4];
#pragma unroll
        for (int mt = 0; mt < 2; mt++)
#pragma unroll
            for (int r = 0; r < 4; r++) gp[mt][r] = 0.f;
#pragma unroll
        for (int nt = 2; nt < 4; nt++) {
            float wg = Wg2[(w * 2 + nt - 2) * 16 + l16];
#pragma unroll
            for (int mt = 0; mt < 2; mt++)
#pragma unroll
                for (int r = 0; r < 4; r++)
                    gp[mt][r] += fmaxf(acc[mt][nt][r], 0.f) * wg;
        }
#pragma unroll
        for (int mask = 1; mask < 16; mask <<= 1)
#pragma unroll
            for (int mt = 0; mt < 2; mt++)
#pragma unroll
                for (int r = 0; r < 4; r++)
                    gp[mt][r] += __shfl_xor(gp[mt][r], mask, 64);
        if (l16 == 0) {
#pragma unroll
            for (int mt = 0; mt < 2; mt++)
#pragma unroll
                for (int r = 0; r < 4; r++)
                    gred[w][mt * 16 + quad * 4 + r] = gp[mt][r];
        }
    }
    __syncthreads();                         // B3: HF + gred ready

    {   // ---- GEMM2 (all 4 waves, col-tile w) + sigmoid + M pack ----
        f32x4 acc2[2];
        float b2 = be2[w * 16 + l16];
#pragma unroll
        for (int mt = 0; mt < 2; mt++) { f32x4 v = {b2, b2, b2, b2}; acc2[mt] = v; }
#pragma unroll
        for (int kc = 0; kc < 4; kc++) {
            bf16x8 c2 = We2F[(kc * 4 + w) * 64 + lane];
#pragma unroll
            for (int mt = 0; mt < 2; mt++)
                acc2[mt] = __builtin_amdgcn_mfma_f32_16x16x32_bf16(
                    U.s.HF[(kc * 2 + mt) * 64 + lane], c2, acc2[mt], 0, 0, 0);
        }

        // redundant per-lane sigmoid from gred (lanes 32-63 mirror 0-31)
        float wgtreg;
        {
            int e = lane & 31;
            float g = bg2[0] + gred[0][e] + gred[1][e] + gred[2][e] + gred[3][e];
            wgtreg = 1.f / (1.f + __expf(-g));
        }

#pragma unroll
        for (int mt = 0; mt < 2; mt++)
#pragma unroll
            for (int r = 0; r < 4; r++) {
                int edge = mt * 16 + quad * 4 + r;
                float wg = __shfl(wgtreg, edge, 64);
                U.s.M[edge * 68 + w * 16 + l16] =
                    (_Float16)(acc2[mt][r] * wg);
            }
    }
    __syncthreads();                         // B4: M ready

    // ---- scatter: all 4 waves, packed v2f16 atomics ----
    // thread t, step k: edge = (t>>5) + 8k, pair p = t&31.
    // per wave-instr: 2 rows x 128 B = 4 cachelines x 16 lanes.
    {
        const int p = t & 31, eh = t >> 5;
        char* base = (char*)magg_rows;
#pragma unroll
        for (int k = 0; k < 4; k++) {
            int e = eh + k * 8;
            f16x2 v = *(const f16x2*)&U.s.M[e * 68 + p * 2];
            pk_atomic_add_f16(base + (long)tgt_s[e] * 256 + p * 4, v);
        }
    }
}

// ------- node kernel (R13): 256 thr, 32 nodes/block, 1563 blocks -----------
__global__ __launch_bounds__(256, 8) void node_kernel(
    const float* __restrict__ m_agg_w,
    const bf16x8* __restrict__ Wn1F, const bf16x8* __restrict__ Wn2F,
    const float* __restrict__ bn1, const float* __restrict__ bn2,
    float* __restrict__ outp)     // rows: f16 acc | bf16 z, then output
{
    __shared__ bf16x8 XF[512];    // 8 KB: tiles (kcs*2+mt), kcs<4, mt<2
    __shared__ bf16x8 HF[512];    // 8 KB (separate -> no hazard barrier)
    const int t = threadIdx.x;
    const int n0 = blockIdx.x * 32;
    const int lane = t & 63, w = t >> 6;     // w 0..3
    const int quad = lane >> 4, l16 = lane & 15;

    {   // gather: 8 threads/node; halves: z-bf16 | m_agg(f16) + m_agg_w
        int nn = t >> 3, q = t & 7;          // nn 0..31
        int mt = nn >> 4, l16e = nn & 15;
        int node = n0 + nn; if (node >= NN) node = NN - 1;
        int half = q >> 2, sub = q & 3;
        bf16x8 c0, c1;
        if (half == 0) {
            const bf16x8* zr = (const bf16x8*)((const char*)outp + (long)node * 256 + 128) + sub * 2;
            c0 = zr[0]; c1 = zr[1];
        } else {
            const f16x8* mr = (const f16x8*)((const char*)outp + (long)node * 256) + sub * 2;
            f16x8 r0 = mr[0], r1 = mr[1];
            const float* mw = m_agg_w + sub * 16;
#pragma unroll
            for (int i = 0; i < 8; i++) {
                c0[i] = (__bf16)((float)r0[i] + mw[i]);
                c1[i] = (__bf16)((float)r1[i] + mw[i + 8]);
            }
        }
        int kcs = (sub >> 1) + half * 2, qa = (sub & 1) * 2;
        XF[(kcs * 2 + mt) * 64 + qa * 16 + l16e]       = c0;
        XF[(kcs * 2 + mt) * 64 + (qa + 1) * 16 + l16e] = c1;
    }
    __syncthreads();                         // B1: XF ready

    // GEMM1: wave owns col-tiles 2w, 2w+1 of H (128 cols)
    f32x4 acc[2][2];
#pragma unroll
    for (int nt2 = 0; nt2 < 2; nt2++) {
        float b = bn1[(w * 2 + nt2) * 16 + l16];
#pragma unroll
        for (int mt = 0; mt < 2; mt++) { f32x4 v = {b, b, b, b}; acc[mt][nt2] = v; }
    }
#pragma unroll
    for (int kc = 0; kc < 4; kc++) {
        bf16x8 b0 = Wn1F[(kc * 8 + w * 2) * 64 + lane];
        bf16x8 b1 = Wn1F[(kc * 8 + w * 2 + 1) * 64 + lane];
#pragma unroll
        for (int mt = 0; mt < 2; mt++) {
            bf16x8 af = XF[(kc * 2 + mt) * 64 + lane];
            acc[mt][0] = __builtin_amdgcn_mfma_f32_16x16x32_bf16(af, b0, acc[mt][0], 0, 0, 0);
            acc[mt][1] = __builtin_amdgcn_mfma_f32_16x16x32_bf16(af, b1, acc[mt][1], 0, 0, 0);
        }
    }

    {   // relu + transpose -> HF (separate buffer: no barrier needed)
        __bf16* HFp = (__bf16*)HF;
#pragma unroll
        for (int nt2 = 0; nt2 < 2; nt2++) {
            int cw = (w * 2 + nt2) * 16 + l16;
            int kc2 = cw >> 5, quad2 = (cw >> 3) & 3, ii = cw & 7;
#pragma unroll
            for (int mt = 0; mt < 2; mt++)
#pragma unroll
                for (int r = 0; r < 4; r++)
                    HFp[(((kc2 * 2 + mt) * 64) + quad2 * 16 + quad * 4 + r) * 8 + ii] =
                        (__bf16)fmaxf(acc[mt][nt2][r], 0.f);
        }
    }
    __syncthreads();                         // B2: HF ready

    {   // GEMM2 + store: wave w = out col-tile w
        f32x4 acc2[2];
        float b2 = bn2[w * 16 + l16];
#pragma unroll
        for (int m = 0; m < 2; m++) { f32x4 v = {b2, b2, b2, b2}; acc2[m] = v; }
#pragma unroll
        for (int kc = 0; kc < 4; kc++) {
            bf16x8 b2f = Wn2F[(kc * 4 + w) * 64 + lane];
#pragma unroll
            for (int m = 0; m < 2; m++)
                acc2[m] = __builtin_amdgcn_mfma_f32_16x16x32_bf16(
                    HF[(kc * 2 + m) * 64 + lane], b2f, acc2[m], 0, 0, 0);
        }
#pragma unroll
        for (int m = 0; m < 2; m++)
#pragma unroll
            for (int r = 0; r < 4; r++) {
                int node = n0 + m * 16 + quad * 4 + r;
                if (node < NN)
                    outp[(long)node * 64 + w * 16 + l16] = acc2[m][r];
            }
    }
}

extern "C" void kernel_launch(void* const* d_in, const int* in_sizes, int n_in,
                              void* d_out, int out_size, void* d_ws, size_t ws_size,
                              hipStream_t stream)
{
    const float* z_h       = (const float*)d_in[0];
    const float* pos_world = (const float*)d_in[1];
    const int*   ei        = (const int*)d_in[2];
    const float* We1 = (const float*)d_in[3];  const float* be1 = (const float*)d_in[4];
    const float* We2 = (const float*)d_in[5];  const float* be2 = (const float*)d_in[6];
    const float* Wg1 = (const float*)d_in[7];  const float* bg1 = (const float*)d_in[8];
    const float* Wg2 = (const float*)d_in[9];  const float* bg2 = (const float*)d_in[10];
    const float* Wn1 = (const float*)d_in[11]; const float* bn1 = (const float*)d_in[12];
    const float* Wn2 = (const float*)d_in[13]; const float* bn2 = (const float*)d_in[14];
    const float* Ww1 = (const float*)d_in[15]; const float* bw1 = (const float*)d_in[16];
    const float* Ww2 = (const float*)d_in[17]; const float* bw2 = (const float*)d_in[18];

    float*  outp    = (float*)d_out;
    float*  m_agg_w = (float*)d_ws;         // 64 floats
    bf16x8* wsF     = (bf16x8*)((char*)d_ws + 256);

    prep<<<(NN * 8 + 255) / 256, 256, 0, stream>>>(
        We1, Wg1, We2, Wn1, Wn2, Ww1, Ww2, wsF, z_h, outp, m_agg_w);
    fused_kernel<<<EBLOCKS + WBLOCKS, 256, 0, stream>>>(
        z_h, ei, wsF + WE1F_OFF, wsF + WE2F_OFF,
        be1, be2, bg1, Wg2, bg2,
        pos_world, wsF + WW1F_OFF, wsF + WW2F_OFF, bw1, bw2,
        outp, m_agg_w);
    node_kernel<<<(NN + 31) / 32, 256, 0, stream>>>(
        m_agg_w, wsF + WN1F_OFF, wsF + WN2F_OFF, bn1, bn2, outp);
}

// Round 14
// 270.180 us; speedup vs baseline: 1.0407x; 1.0407x over previous
//
#include <hip/hip_runtime.h>
#include <math.h>

#define NN 50000
#define NE 800000
#define EBLOCKS (NE / 32)          // 25000 edge blocks (32 edges, 256 thr)
#define WBLOCKS ((NN + 63) / 64)   // 782 world blocks

typedef float     f32x4  __attribute__((ext_vector_type(4)));
typedef __bf16    bf16x8 __attribute__((ext_vector_type(8)));
typedef _Float16  f16x2  __attribute__((ext_vector_type(2)));
typedef _Float16  f16x8  __attribute__((ext_vector_type(8)));

// ws layout: [0,256) m_agg_w (64 f32). [256,...) bf16 weight fragments.
#define WE1F_OFF 0        // 5120: We1||Wg1  (kc<5, ct<16)  K 136->160
#define WE2F_OFF 5120     // 1024: We2       (kc<4, ct<4)
#define WN1F_OFF 6144     // 2048: Wn1       (kc<4, ct<8)
#define WN2F_OFF 8192     // 1024: Wn2       (kc<4, ct<4)
#define WW1F_OFF 9216     // 1536: Ww1       (kc<3, ct<8)   K 67->96
#define WW2F_OFF 10752    // 1024: Ww2       (kc<4, ct<4)
#define NCHUNKS  11776

// d_out row n (256 B): first 128 B = f16[64] m_agg accumulator (atomic
// target, zeroed by prep); second 128 B = bf16[64] z_h row n (gather table,
// written by prep). node_kernel block n reads both halves of its rows then
// overwrites them -> race-free, zero extra workspace.

__device__ inline bf16x8 pack8(float4 a, float4 b) {
    bf16x8 r;
    r[0] = (__bf16)a.x; r[1] = (__bf16)a.y; r[2] = (__bf16)a.z; r[3] = (__bf16)a.w;
    r[4] = (__bf16)b.x; r[5] = (__bf16)b.y; r[6] = (__bf16)b.z; r[7] = (__bf16)b.w;
    return r;
}

// packed 2x f16 atomic fadd (global_atomic_pk_add_f16, gfx90a+).
__device__ inline void pk_atomic_add_f16(void* addr, f16x2 v) {
#if __has_builtin(__builtin_amdgcn_global_atomic_fadd_v2f16)
    __builtin_amdgcn_global_atomic_fadd_v2f16((f16x2*)addr, v);
#else
    asm volatile("global_atomic_pk_add_f16 %0, %1, off"
                 :: "v"(addr), "v"(v) : "memory");
#endif
}

// ------- single prep kernel: weight fragments + z-bf16 table + zeroing -----
__global__ __launch_bounds__(256) void prep(
    const float* __restrict__ We1, const float* __restrict__ Wg1,
    const float* __restrict__ We2, const float* __restrict__ Wn1,
    const float* __restrict__ Wn2, const float* __restrict__ Ww1,
    const float* __restrict__ Ww2, bf16x8* __restrict__ wsF,
    const float* __restrict__ z, float* __restrict__ db,
    float* __restrict__ m_agg_w)
{
    const int c = blockIdx.x * 256 + threadIdx.x;

    if (c < 64) m_agg_w[c] = 0.f;

    if (c < NN * 8) {      // z-table (2nd half) + zero f16 acc (1st half)
        int node = c >> 3, q = c & 7;
        const float4* s = (const float4*)(z + (long)node * 64) + q * 2;
        float4 a = s[0], b = s[1];
        *(bf16x8*)((char*)db + (long)node * 256 + 128 + q * 16) = pack8(a, b);
        float4 zz = {0.f, 0.f, 0.f, 0.f};
        *(float4*)((char*)db + (long)node * 256 + q * 16) = zz;
    }

    if (c >= NCHUNKS) return;
    const int lane = c & 63, l16 = lane & 15, row8 = ((lane >> 4) & 3) * 8;
    bf16x8 p;
    if (c < WE2F_OFF) {                       // We1 || Wg1, pad K 136->160
        int ct = (c >> 6) & 15, kc = c >> 10;
        int col = ct * 16 + l16;
        const float* src = (col < 128) ? (We1 + col) : (Wg1 + (col - 128));
#pragma unroll
        for (int i = 0; i < 8; i++) {
            int r = kc * 32 + row8 + i;
            p[i] = (__bf16)((r < 136) ? src[(size_t)r * 128] : 0.f);
        }
    } else if (c < WN1F_OFF) {
        int cc = c - WE2F_OFF; int ct = (cc >> 6) & 3, kc = cc >> 8;
        int col = ct * 16 + l16;
#pragma unroll
        for (int i = 0; i < 8; i++)
            p[i] = (__bf16)We2[(size_t)(kc * 32 + row8 + i) * 64 + col];
    } else if (c < WN2F_OFF) {
        int cc = c - WN1F_OFF; int ct = (cc >> 6) & 7, kc = cc >> 9;
        int col = ct * 16 + l16;
#pragma unroll
        for (int i = 0; i < 8; i++)
            p[i] = (__bf16)Wn1[(size_t)(kc * 32 + row8 + i) * 128 + col];
    } else if (c < WW1F_OFF) {
        int cc = c - WN2F_OFF; int ct = (cc >> 6) & 3, kc = cc >> 8;
        int col = ct * 16 + l16;
#pragma unroll
        for (int i = 0; i < 8; i++)
            p[i] = (__bf16)Wn2[(size_t)(kc * 32 + row8 + i) * 64 + col];
    } else if (c < WW2F_OFF) {                // Ww1, pad K 67->96
        int cc = c - WW1F_OFF; int ct = (cc >> 6) & 7, kc = cc >> 9;
        int col = ct * 16 + l16;
#pragma unroll
        for (int i = 0; i < 8; i++) {
            int r = kc * 32 + row8 + i;
            p[i] = (__bf16)((r < 67) ? Ww1[(size_t)r * 128 + col] : 0.f);
        }
    } else {
        int cc = c - WW2F_OFF; int ct = (cc >> 6) & 3, kc = cc >> 8;
        int col = ct * 16 + l16;
#pragma unroll
        for (int i = 0; i < 8; i++)
            p[i] = (__bf16)Ww2[(size_t)(kc * 32 + row8 + i) * 64 + col];
    }
    wsF[c] = p;
}

// --------- fused edge + world kernel: blocks [0,EBLOCKS) = edges, rest = world
// Edge path (R14 = R12 exactly): 32 edges/block, 4 waves, launch_bounds
// (256,6) -- the measured L2-pressure optimum (R13's 8 blocks/CU thrashed
// L2: WRITE 100->271 MB, fused 171->190 us). Wave owns 2 msg + 2 gate GEMM1
// col-tiles; all 4 waves active in every phase.
union FusedLds {
    bf16x8 XF[1024];                    // world gather 12 tiles / world HF 16 KB
    struct {
        bf16x8   HF[512];               // edge HF 8 KB (aliases dead XF)
        _Float16 M[32 * 68];            // 4.4 KB
    } s;
};

__global__ __launch_bounds__(256, 6) void fused_kernel(
    const float* __restrict__ z_h, const int* __restrict__ ei,
    const bf16x8* __restrict__ We1F, const bf16x8* __restrict__ We2F,
    const float* __restrict__ be1, const float* __restrict__ be2,
    const float* __restrict__ bg1, const float* __restrict__ Wg2,
    const float* __restrict__ bg2,
    const float* __restrict__ pos_world,
    const bf16x8* __restrict__ Ww1F, const bf16x8* __restrict__ Ww2F,
    const float* __restrict__ bw1, const float* __restrict__ bw2,
    float* __restrict__ magg_rows,     // = d_out; acc first half, z-bf16 second
    float* __restrict__ m_agg_w)
{
    __shared__ FusedLds U;
    __shared__ int   tgt_s[32];
    __shared__ float gred[4][32];

    const int t = threadIdx.x;               // 0..255
    const int lane = t & 63, w = t >> 6;     // w 0..3
    const int quad = lane >> 4, l16 = lane & 15;

    if (blockIdx.x >= EBLOCKS) {
        // ================= world path (256-thread, 64 nodes) ================
        const int n0 = (blockIdx.x - EBLOCKS) * 64;
        {   // gather: 4 threads/node
            int nn = t >> 2, q = t & 3;
            int mt = nn >> 4, l16e = nn & 15;
            int node = n0 + nn; if (node >= NN) node = NN - 1;
            const float4* zr = (const float4*)(z_h + (long)node * 64) + q * 4;
            float4 a0 = zr[0], a1 = zr[1], a2 = zr[2], a3 = zr[3];
            int kcs = q >> 1, qa = (q & 1) * 2;
            U.XF[(kcs * 4 + mt) * 64 + qa * 16 + l16e]       = pack8(a0, a1);
            U.XF[(kcs * 4 + mt) * 64 + (qa + 1) * 16 + l16e] = pack8(a2, a3);
            if (q == 0) {
                bf16x8 f;
#pragma unroll
                for (int i = 0; i < 8; i++) f[i] = (__bf16)0.f;
                f[0] = (__bf16)(a0.x - pos_world[0]);
                f[1] = (__bf16)(a0.y - pos_world[1]);
                f[2] = (__bf16)(a0.z - pos_world[2]);
                U.XF[(8 + mt) * 64 + l16e] = f;
            } else {
                bf16x8 z8;
#pragma unroll
                for (int i = 0; i < 8; i++) z8[i] = (__bf16)0.f;
                U.XF[(8 + mt) * 64 + q * 16 + l16e] = z8;
            }
        }
        __syncthreads();

        f32x4 acc[4][2];
#pragma unroll
        for (int nt2 = 0; nt2 < 2; nt2++) {
            float b = bw1[(w * 2 + nt2) * 16 + l16];
#pragma unroll
            for (int mt = 0; mt < 4; mt++) { f32x4 v = {b, b, b, b}; acc[mt][nt2] = v; }
        }
#pragma unroll
        for (int kc = 0; kc < 3; kc++) {
#pragma unroll
            for (int nt2 = 0; nt2 < 2; nt2++) {
                bf16x8 bfr = Ww1F[(kc * 8 + w * 2 + nt2) * 64 + lane];
#pragma unroll
                for (int mt = 0; mt < 4; mt++)
                    acc[mt][nt2] = __builtin_amdgcn_mfma_f32_16x16x32_bf16(
                        U.XF[(kc * 4 + mt) * 64 + lane], bfr, acc[mt][nt2], 0, 0, 0);
            }
        }
        __syncthreads();

        {   // relu + transpose -> HF (aliases XF base)
            __bf16* HFp = (__bf16*)U.XF;
#pragma unroll
            for (int nt2 = 0; nt2 < 2; nt2++) {
                int cw = (w * 2 + nt2) * 16 + l16;
                int kc2 = cw >> 5, quad2 = (cw >> 3) & 3, ii = cw & 7;
#pragma unroll
                for (int mt = 0; mt < 4; mt++)
#pragma unroll
                    for (int r = 0; r < 4; r++)
                        HFp[(((kc2 * 4 + mt) * 64) + quad2 * 16 + quad * 4 + r) * 8 + ii] =
                            (__bf16)fmaxf(acc[mt][nt2][r], 0.f);
            }
        }
        __syncthreads();

        {   // GEMM2 + masked column-sum (wave w = col-tile, mh loop)
            f32x4 acc2[2][2];
            float b2 = bw2[w * 16 + l16];
#pragma unroll
            for (int mh = 0; mh < 2; mh++)
#pragma unroll
                for (int m = 0; m < 2; m++) { f32x4 v = {b2, b2, b2, b2}; acc2[mh][m] = v; }
#pragma unroll
            for (int kc = 0; kc < 4; kc++) {
                bf16x8 b2f = Ww2F[(kc * 4 + w) * 64 + lane];
#pragma unroll
                for (int mh = 0; mh < 2; mh++)
#pragma unroll
                    for (int m = 0; m < 2; m++)
                        acc2[mh][m] = __builtin_amdgcn_mfma_f32_16x16x32_bf16(
                            U.XF[(kc * 4 + mh * 2 + m) * 64 + lane], b2f, acc2[mh][m], 0, 0, 0);
            }
            float s = 0.f;
#pragma unroll
            for (int mh = 0; mh < 2; mh++)
#pragma unroll
                for (int m = 0; m < 2; m++)
#pragma unroll
                    for (int r = 0; r < 4; r++) {
                        int node = n0 + (mh * 2 + m) * 16 + quad * 4 + r;
                        s += (node < NN) ? acc2[mh][m][r] : 0.f;
                    }
            s += __shfl_xor(s, 16, 64);
            s += __shfl_xor(s, 32, 64);
            if (quad == 0) atomicAdd(m_agg_w + w * 16 + l16, s);
        }
        return;
    }

    // ================= edge path (32 edges/block, bf16 table gather) ========
    const int e0 = blockIdx.x * 32;          // NE % 32 == 0

    {   // ---- gather: 8 threads/edge, thread q loads 16B chunk q of BOTH rows
        const int ee = t >> 3, q = t & 7;    // ee 0..31
        const int mt = ee >> 4, l16e = ee & 15;
        const int eg = e0 + ee;
        const int rs = ei[eg], rt = ei[NE + eg];
        const bf16x8* zs = (const bf16x8*)((const char*)magg_rows + (long)rs * 256 + 128);
        const bf16x8* zt = (const bf16x8*)((const char*)magg_rows + (long)rt * 256 + 128);
        bf16x8 sa = zs[q];                   // src cols q*8 .. q*8+7
        bf16x8 ta = zt[q];                   // tgt cols q*8 .. q*8+7
        const int kcs = q >> 2, qslot = q & 3;
        U.XF[(kcs * 2 + mt) * 64 + qslot * 16 + l16e]       = sa;
        U.XF[((kcs + 2) * 2 + mt) * 64 + qslot * 16 + l16e] = ta;
        if (q == 4) tgt_s[ee] = rt;
        if (q == 0) {        // edge features (cols 128..135) from bf16 chunk 0
            float dx = (float)sa[0] - (float)ta[0];
            float dy = (float)sa[1] - (float)ta[1];
            float dz = (float)sa[2] - (float)ta[2];
            float ax = (float)sa[3], ay = (float)sa[4], az = (float)sa[5];
            float bx = (float)ta[3], by = (float)ta[4], bz = (float)ta[5];
            float cx = ay * bz - az * by;
            float cy = az * bx - ax * bz;
            float cz = ax * by - ay * bx;
            bf16x8 f;
            f[0] = (__bf16)dx; f[1] = (__bf16)dy; f[2] = (__bf16)dz;
            f[3] = (__bf16)(dx * dx + dy * dy + dz * dz);
            f[4] = (__bf16)cx; f[5] = (__bf16)cy; f[6] = (__bf16)cz;
            f[7] = (__bf16)sqrtf(cx * cx + cy * cy + cz * cz);
            U.XF[(8 + mt) * 64 + l16e] = f;
        } else if (q >= 5) { // zero pad (cols 136..159)
            bf16x8 z;
#pragma unroll
            for (int i = 0; i < 8; i++) z[i] = (__bf16)0.f;
            U.XF[(8 + mt) * 64 + (q - 4) * 16 + l16e] = z;
        }
    }
    __syncthreads();                         // B1: XF + tgt_s ready

    // ---- GEMM1: wave owns 4 col-tiles (msg 2w,2w+1; gate 8+2w,8+2w+1) ----
    f32x4 acc[2][4];
#pragma unroll
    for (int nt = 0; nt < 4; nt++) {
        float b = (nt < 2) ? be1[(w * 2 + nt) * 16 + l16]
                           : bg1[(w * 2 + nt - 2) * 16 + l16];
#pragma unroll
        for (int mt = 0; mt < 2; mt++) { f32x4 v = {b, b, b, b}; acc[mt][nt] = v; }
    }
#pragma unroll
    for (int kc = 0; kc < 5; kc++) {
        bf16x8 bf0 = We1F[(kc * 16 + w * 2) * 64 + lane];
        bf16x8 bf1 = We1F[(kc * 16 + w * 2 + 1) * 64 + lane];
        bf16x8 bf2 = We1F[(kc * 16 + 8 + w * 2) * 64 + lane];
        bf16x8 bf3 = We1F[(kc * 16 + 8 + w * 2 + 1) * 64 + lane];
#pragma unroll
        for (int mt = 0; mt < 2; mt++) {
            bf16x8 af = U.XF[(kc * 2 + mt) * 64 + lane];
            acc[mt][0] = __builtin_amdgcn_mfma_f32_16x16x32_bf16(af, bf0, acc[mt][0], 0, 0, 0);
            acc[mt][1] = __builtin_amdgcn_mfma_f32_16x16x32_bf16(af, bf1, acc[mt][1], 0, 0, 0);
            acc[mt][2] = __builtin_amdgcn_mfma_f32_16x16x32_bf16(af, bf2, acc[mt][2], 0, 0, 0);
            acc[mt][3] = __builtin_amdgcn_mfma_f32_16x16x32_bf16(af, bf3, acc[mt][3], 0, 0, 0);
        }
    }
    __syncthreads();                         // B2: XF reads done (HF may overwrite)

    {   // ---- all waves: relu+transpose msg tiles -> HF, gate partials ----
        __bf16* HFp = (__bf16*)U.s.HF;
#pragma unroll
        for (int nt = 0; nt < 2; nt++) {
            int cw = (w * 2 + nt) * 16 + l16;
            int kc2 = cw >> 5, quad2 = (cw >> 3) & 3, ii = cw & 7;
#pragma unroll
            for (int mt = 0; mt < 2; mt++)
#pragma unroll
                for (int r = 0; r < 4; r++)
                    HFp[(((kc2 * 2 + mt) * 64) + quad2 * 16 + quad * 4 + r) * 8 + ii] =
                        (__bf16)fmaxf(acc[mt][nt][r], 0.f);
        }
        float gp[2][4];
#pragma unroll
        for (int mt = 0; mt < 2; mt++)
#pragma unroll
            for (int r = 0; r < 4; r++) gp[mt][r] = 0.f;
#pragma unroll
        for (int nt = 2; nt < 4; nt++) {
            float wg = Wg2[(w * 2 + nt - 2) * 16 + l16];
#pragma unroll
            for (int mt = 0; mt < 2; mt++)
#pragma unroll
                for (int r = 0; r < 4; r++)
                    gp[mt][r] += fmaxf(acc[mt][nt][r], 0.f) * wg;
        }
#pragma unroll
        for (int mask = 1; mask < 16; mask <<= 1)
#pragma unroll
            for (int mt = 0; mt < 2; mt++)
#pragma unroll
                for (int r = 0; r < 4; r++)
                    gp[mt][r] += __shfl_xor(gp[mt][r], mask, 64);
        if (l16 == 0) {
#pragma unroll
            for (int mt = 0; mt < 2; mt++)
#pragma unroll
                for (int r = 0; r < 4; r++)
                    gred[w][mt * 16 + quad * 4 + r] = gp[mt][r];
        }
    }
    __syncthreads();                         // B3: HF + gred ready

    {   // ---- GEMM2 (all 4 waves, col-tile w) + sigmoid + M pack ----
        f32x4 acc2[2];
        float b2 = be2[w * 16 + l16];
#pragma unroll
        for (int mt = 0; mt < 2; mt++) { f32x4 v = {b2, b2, b2, b2}; acc2[mt] = v; }
#pragma unroll
        for (int kc = 0; kc < 4; kc++) {
            bf16x8 c2 = We2F[(kc * 4 + w) * 64 + lane];
#pragma unroll
            for (int mt = 0; mt < 2; mt++)
                acc2[mt] = __builtin_amdgcn_mfma_f32_16x16x32_bf16(
                    U.s.HF[(kc * 2 + mt) * 64 + lane], c2, acc2[mt], 0, 0, 0);
        }

        // redundant per-lane sigmoid from gred (lanes 32-63 mirror 0-31)
        float wgtreg;
        {
            int e = lane & 31;
            float g = bg2[0] + gred[0][e] + gred[1][e] + gred[2][e] + gred[3][e];
            wgtreg = 1.f / (1.f + __expf(-g));
        }

#pragma unroll
        for (int mt = 0; mt < 2; mt++)
#pragma unroll
            for (int r = 0; r < 4; r++) {
                int edge = mt * 16 + quad * 4 + r;
                float wg = __shfl(wgtreg, edge, 64);
                U.s.M[edge * 68 + w * 16 + l16] =
                    (_Float16)(acc2[mt][r] * wg);
            }
    }
    __syncthreads();                         // B4: M ready

    // ---- scatter: all 4 waves, packed v2f16 atomics ----
    // thread t, step k: edge = (t>>5) + 8k, pair p = t&31.
    // per wave-instr: 2 rows x 128 B = 4 cachelines x 16 lanes.
    {
        const int p = t & 31, eh = t >> 5;
        char* base = (char*)magg_rows;
#pragma unroll
        for (int k = 0; k < 4; k++) {
            int e = eh + k * 8;
            f16x2 v = *(const f16x2*)&U.s.M[e * 68 + p * 2];
            pk_atomic_add_f16(base + (long)tgt_s[e] * 256 + p * 4, v);
        }
    }
}

// ------- node kernel (R13): 256 thr, 32 nodes/block, 1563 blocks -----------
__global__ __launch_bounds__(256, 8) void node_kernel(
    const float* __restrict__ m_agg_w,
    const bf16x8* __restrict__ Wn1F, const bf16x8* __restrict__ Wn2F,
    const float* __restrict__ bn1, const float* __restrict__ bn2,
    float* __restrict__ outp)     // rows: f16 acc | bf16 z, then output
{
    __shared__ bf16x8 XF[512];    // 8 KB: tiles (kcs*2+mt), kcs<4, mt<2
    __shared__ bf16x8 HF[512];    // 8 KB (separate -> no hazard barrier)
    const int t = threadIdx.x;
    const int n0 = blockIdx.x * 32;
    const int lane = t & 63, w = t >> 6;     // w 0..3
    const int quad = lane >> 4, l16 = lane & 15;

    {   // gather: 8 threads/node; halves: z-bf16 | m_agg(f16) + m_agg_w
        int nn = t >> 3, q = t & 7;          // nn 0..31
        int mt = nn >> 4, l16e = nn & 15;
        int node = n0 + nn; if (node >= NN) node = NN - 1;
        int half = q >> 2, sub = q & 3;
        bf16x8 c0, c1;
        if (half == 0) {
            const bf16x8* zr = (const bf16x8*)((const char*)outp + (long)node * 256 + 128) + sub * 2;
            c0 = zr[0]; c1 = zr[1];
        } else {
            const f16x8* mr = (const f16x8*)((const char*)outp + (long)node * 256) + sub * 2;
            f16x8 r0 = mr[0], r1 = mr[1];
            const float* mw = m_agg_w + sub * 16;
#pragma unroll
            for (int i = 0; i < 8; i++) {
                c0[i] = (__bf16)((float)r0[i] + mw[i]);
                c1[i] = (__bf16)((float)r1[i] + mw[i + 8]);
            }
        }
        int kcs = (sub >> 1) + half * 2, qa = (sub & 1) * 2;
        XF[(kcs * 2 + mt) * 64 + qa * 16 + l16e]       = c0;
        XF[(kcs * 2 + mt) * 64 + (qa + 1) * 16 + l16e] = c1;
    }
    __syncthreads();                         // B1: XF ready

    // GEMM1: wave owns col-tiles 2w, 2w+1 of H (128 cols)
    f32x4 acc[2][2];
#pragma unroll
    for (int nt2 = 0; nt2 < 2; nt2++) {
        float b = bn1[(w * 2 + nt2) * 16 + l16];
#pragma unroll
        for (int mt = 0; mt < 2; mt++) { f32x4 v = {b, b, b, b}; acc[mt][nt2] = v; }
    }
#pragma unroll
    for (int kc = 0; kc < 4; kc++) {
        bf16x8 b0 = Wn1F[(kc * 8 + w * 2) * 64 + lane];
        bf16x8 b1 = Wn1F[(kc * 8 + w * 2 + 1) * 64 + lane];
#pragma unroll
        for (int mt = 0; mt < 2; mt++) {
            bf16x8 af = XF[(kc * 2 + mt) * 64 + lane];
            acc[mt][0] = __builtin_amdgcn_mfma_f32_16x16x32_bf16(af, b0, acc[mt][0], 0, 0, 0);
            acc[mt][1] = __builtin_amdgcn_mfma_f32_16x16x32_bf16(af, b1, acc[mt][1], 0, 0, 0);
        }
    }

    {   // relu + transpose -> HF (separate buffer: no barrier needed)
        __bf16* HFp = (__bf16*)HF;
#pragma unroll
        for (int nt2 = 0; nt2 < 2; nt2++) {
            int cw = (w * 2 + nt2) * 16 + l16;
            int kc2 = cw >> 5, quad2 = (cw >> 3) & 3, ii = cw & 7;
#pragma unroll
            for (int mt = 0; mt < 2; mt++)
#pragma unroll
                for (int r = 0; r < 4; r++)
                    HFp[(((kc2 * 2 + mt) * 64) + quad2 * 16 + quad * 4 + r) * 8 + ii] =
                        (__bf16)fmaxf(acc[mt][nt2][r], 0.f);
        }
    }
    __syncthreads();                         // B2: HF ready

    {   // GEMM2 + store: wave w = out col-tile w
        f32x4 acc2[2];
        float b2 = bn2[w * 16 + l16];
#pragma unroll
        for (int m = 0; m < 2; m++) { f32x4 v = {b2, b2, b2, b2}; acc2[m] = v; }
#pragma unroll
        for (int kc = 0; kc < 4; kc++) {
            bf16x8 b2f = Wn2F[(kc * 4 + w) * 64 + lane];
#pragma unroll
            for (int m = 0; m < 2; m++)
                acc2[m] = __builtin_amdgcn_mfma_f32_16x16x32_bf16(
                    HF[(kc * 2 + m) * 64 + lane], b2f, acc2[m], 0, 0, 0);
        }
#pragma unroll
        for (int m = 0; m < 2; m++)
#pragma unroll
            for (int r = 0; r < 4; r++) {
                int node = n0 + m * 16 + quad * 4 + r;
                if (node < NN)
                    outp[(long)node * 64 + w * 16 + l16] = acc2[m][r];
            }
    }
}

extern "C" void kernel_launch(void* const* d_in, const int* in_sizes, int n_in,
                              void* d_out, int out_size, void* d_ws, size_t ws_size,
                              hipStream_t stream)
{
    const float* z_h       = (const float*)d_in[0];
    const float* pos_world = (const float*)d_in[1];
    const int*   ei        = (const int*)d_in[2];
    const float* We1 = (const float*)d_in[3];  const float* be1 = (const float*)d_in[4];
    const float* We2 = (const float*)d_in[5];  const float* be2 = (const float*)d_in[6];
    const float* Wg1 = (const float*)d_in[7];  const float* bg1 = (const float*)d_in[8];
    const float* Wg2 = (const float*)d_in[9];  const float* bg2 = (const float*)d_in[10];
    const float* Wn1 = (const float*)d_in[11]; const float* bn1 = (const float*)d_in[12];
    const float* Wn2 = (const float*)d_in[13]; const float* bn2 = (const float*)d_in[14];
    const float* Ww1 = (const float*)d_in[15]; const float* bw1 = (const float*)d_in[16];
    const float* Ww2 = (const float*)d_in[17]; const float* bw2 = (const float*)d_in[18];

    float*  outp    = (float*)d_out;
    float*  m_agg_w = (float*)d_ws;         // 64 floats
    bf16x8* wsF     = (bf16x8*)((char*)d_ws + 256);

    prep<<<(NN * 8 + 255) / 256, 256, 0, stream>>>(
        We1, Wg1, We2, Wn1, Wn2, Ww1, Ww2, wsF, z_h, outp, m_agg_w);
    fused_kernel<<<EBLOCKS + WBLOCKS, 256, 0, stream>>>(
        z_h, ei, wsF + WE1F_OFF, wsF + WE2F_OFF,
        be1, be2, bg1, Wg2, bg2,
        pos_world, wsF + WW1F_OFF, wsF + WW2F_OFF, bw1, bw2,
        outp, m_agg_w);
    node_kernel<<<(NN + 31) / 32, 256, 0, stream>>>(
        m_agg_w, wsF + WN1F_OFF, wsF + WN2F_OFF, bn1, bn2, outp);
}

// Round 15
// 263.280 us; speedup vs baseline: 1.0680x; 1.0262x over previous
//
#include <hip/hip_runtime.h>
#include <math.h>

#define NN 50000
#define NE 800000
#define EBLOCKS (NE / 32)          // 25000 edge blocks (32 edges, 256 thr)
#define WBLOCKS ((NN + 63) / 64)   // 782 world blocks

typedef float     f32x4  __attribute__((ext_vector_type(4)));
typedef __bf16    bf16x8 __attribute__((ext_vector_type(8)));
typedef _Float16  f16x2  __attribute__((ext_vector_type(2)));
typedef _Float16  f16x8  __attribute__((ext_vector_type(8)));

// ws layout: [0,256) m_agg_w (64 f32). [256,...) bf16 weight fragments.
#define WE1F_OFF 0        // 5120: We1||Wg1  (kc<5, ct<16)  K 136->160
#define WE2F_OFF 5120     // 1024: We2       (kc<4, ct<4)
#define WN1F_OFF 6144     // 2048: Wn1       (kc<4, ct<8)
#define WN2F_OFF 8192     // 1024: Wn2       (kc<4, ct<4)
#define WW1F_OFF 9216     // 1536: Ww1       (kc<3, ct<8)   K 67->96
#define WW2F_OFF 10752    // 1024: Ww2       (kc<4, ct<4)
#define NCHUNKS  11776

// d_out row n (256 B): first 128 B = f16[64] m_agg accumulator (atomic
// target, zeroed by prep); second 128 B = bf16[64] z_h row n (gather table,
// written by prep). node_kernel block n reads both halves of its rows then
// overwrites them -> race-free, zero extra workspace.

__device__ inline bf16x8 pack8(float4 a, float4 b) {
    bf16x8 r;
    r[0] = (__bf16)a.x; r[1] = (__bf16)a.y; r[2] = (__bf16)a.z; r[3] = (__bf16)a.w;
    r[4] = (__bf16)b.x; r[5] = (__bf16)b.y; r[6] = (__bf16)b.z; r[7] = (__bf16)b.w;
    return r;
}

__device__ inline float4 add4(float4 a, float4 b) {
    a.x += b.x; a.y += b.y; a.z += b.z; a.w += b.w; return a;
}

// packed 2x f16 atomic fadd (global_atomic_pk_add_f16, gfx90a+).
__device__ inline void pk_atomic_add_f16(void* addr, f16x2 v) {
#if __has_builtin(__builtin_amdgcn_global_atomic_fadd_v2f16)
    __builtin_amdgcn_global_atomic_fadd_v2f16((f16x2*)addr, v);
#else
    asm volatile("global_atomic_pk_add_f16 %0, %1, off"
                 :: "v"(addr), "v"(v) : "memory");
#endif
}

// ------- single prep kernel: weight fragments + z-bf16 table + zeroing -----
__global__ __launch_bounds__(256) void prep(
    const float* __restrict__ We1, const float* __restrict__ Wg1,
    const float* __restrict__ We2, const float* __restrict__ Wn1,
    const float* __restrict__ Wn2, const float* __restrict__ Ww1,
    const float* __restrict__ Ww2, bf16x8* __restrict__ wsF,
    const float* __restrict__ z, float* __restrict__ db,
    float* __restrict__ m_agg_w)
{
    const int c = blockIdx.x * 256 + threadIdx.x;

    if (c < 64) m_agg_w[c] = 0.f;

    if (c < NN * 8) {      // z-table (2nd half) + zero f16 acc (1st half)
        int node = c >> 3, q = c & 7;
        const float4* s = (const float4*)(z + (long)node * 64) + q * 2;
        float4 a = s[0], b = s[1];
        *(bf16x8*)((char*)db + (long)node * 256 + 128 + q * 16) = pack8(a, b);
        float4 zz = {0.f, 0.f, 0.f, 0.f};
        *(float4*)((char*)db + (long)node * 256 + q * 16) = zz;
    }

    if (c >= NCHUNKS) return;
    const int lane = c & 63, l16 = lane & 15, row8 = ((lane >> 4) & 3) * 8;
    bf16x8 p;
    if (c < WE2F_OFF) {                       // We1 || Wg1, pad K 136->160
        int ct = (c >> 6) & 15, kc = c >> 10;
        int col = ct * 16 + l16;
        const float* src = (col < 128) ? (We1 + col) : (Wg1 + (col - 128));
#pragma unroll
        for (int i = 0; i < 8; i++) {
            int r = kc * 32 + row8 + i;
            p[i] = (__bf16)((r < 136) ? src[(size_t)r * 128] : 0.f);
        }
    } else if (c < WN1F_OFF) {
        int cc = c - WE2F_OFF; int ct = (cc >> 6) & 3, kc = cc >> 8;
        int col = ct * 16 + l16;
#pragma unroll
        for (int i = 0; i < 8; i++)
            p[i] = (__bf16)We2[(size_t)(kc * 32 + row8 + i) * 64 + col];
    } else if (c < WN2F_OFF) {
        int cc = c - WN1F_OFF; int ct = (cc >> 6) & 7, kc = cc >> 9;
        int col = ct * 16 + l16;
#pragma unroll
        for (int i = 0; i < 8; i++)
            p[i] = (__bf16)Wn1[(size_t)(kc * 32 + row8 + i) * 128 + col];
    } else if (c < WW1F_OFF) {
        int cc = c - WN2F_OFF; int ct = (cc >> 6) & 3, kc = cc >> 8;
        int col = ct * 16 + l16;
#pragma unroll
        for (int i = 0; i < 8; i++)
            p[i] = (__bf16)Wn2[(size_t)(kc * 32 + row8 + i) * 64 + col];
    } else if (c < WW2F_OFF) {                // Ww1, pad K 67->96
        int cc = c - WW1F_OFF; int ct = (cc >> 6) & 7, kc = cc >> 9;
        int col = ct * 16 + l16;
#pragma unroll
        for (int i = 0; i < 8; i++) {
            int r = kc * 32 + row8 + i;
            p[i] = (__bf16)((r < 67) ? Ww1[(size_t)r * 128 + col] : 0.f);
        }
    } else {
        int cc = c - WW2F_OFF; int ct = (cc >> 6) & 3, kc = cc >> 8;
        int col = ct * 16 + l16;
#pragma unroll
        for (int i = 0; i < 8; i++)
            p[i] = (__bf16)Ww2[(size_t)(kc * 32 + row8 + i) * 64 + col];
    }
    wsF[c] = p;
}

// --------- fused edge + world kernel: blocks [0,EBLOCKS) = edges, rest = world
// Edge path (best measured, R12): 32 edges/block, 4 waves, launch_bounds
// (256,6) = the L2-pressure optimum (8 blocks/CU thrashed L2 in R13:
// WRITE 100->271 MB). Wave owns 2 msg + 2 gate GEMM1 col-tiles; all 4
// waves active in every phase.
union FusedLds {
    bf16x8 XF[1024];                    // world gather 12 tiles / world HF 16 KB
    struct {
        bf16x8   HF[512];               // edge HF 8 KB (aliases dead XF)
        _Float16 M[32 * 68];            // 4.4 KB
    } s;
};

__global__ __launch_bounds__(256, 6) void fused_kernel(
    const float* __restrict__ z_h, const int* __restrict__ ei,
    const bf16x8* __restrict__ We1F, const bf16x8* __restrict__ We2F,
    const float* __restrict__ be1, const float* __restrict__ be2,
    const float* __restrict__ bg1, const float* __restrict__ Wg2,
    const float* __restrict__ bg2,
    const float* __restrict__ pos_world,
    const bf16x8* __restrict__ Ww1F, const bf16x8* __restrict__ Ww2F,
    const float* __restrict__ bw1, const float* __restrict__ bw2,
    float* __restrict__ magg_rows,     // = d_out; acc first half, z-bf16 second
    float* __restrict__ m_agg_w)
{
    __shared__ FusedLds U;
    __shared__ int   tgt_s[32];
    __shared__ float gred[4][32];

    const int t = threadIdx.x;               // 0..255
    const int lane = t & 63, w = t >> 6;     // w 0..3
    const int quad = lane >> 4, l16 = lane & 15;

    if (blockIdx.x >= EBLOCKS) {
        // ================= world path (256-thread, 64 nodes) ================
        const int n0 = (blockIdx.x - EBLOCKS) * 64;
        {   // gather: 4 threads/node
            int nn = t >> 2, q = t & 3;
            int mt = nn >> 4, l16e = nn & 15;
            int node = n0 + nn; if (node >= NN) node = NN - 1;
            const float4* zr = (const float4*)(z_h + (long)node * 64) + q * 4;
            float4 a0 = zr[0], a1 = zr[1], a2 = zr[2], a3 = zr[3];
            int kcs = q >> 1, qa = (q & 1) * 2;
            U.XF[(kcs * 4 + mt) * 64 + qa * 16 + l16e]       = pack8(a0, a1);
            U.XF[(kcs * 4 + mt) * 64 + (qa + 1) * 16 + l16e] = pack8(a2, a3);
            if (q == 0) {
                bf16x8 f;
#pragma unroll
                for (int i = 0; i < 8; i++) f[i] = (__bf16)0.f;
                f[0] = (__bf16)(a0.x - pos_world[0]);
                f[1] = (__bf16)(a0.y - pos_world[1]);
                f[2] = (__bf16)(a0.z - pos_world[2]);
                U.XF[(8 + mt) * 64 + l16e] = f;
            } else {
                bf16x8 z8;
#pragma unroll
                for (int i = 0; i < 8; i++) z8[i] = (__bf16)0.f;
                U.XF[(8 + mt) * 64 + q * 16 + l16e] = z8;
            }
        }
        __syncthreads();

        f32x4 acc[4][2];
#pragma unroll
        for (int nt2 = 0; nt2 < 2; nt2++) {
            float b = bw1[(w * 2 + nt2) * 16 + l16];
#pragma unroll
            for (int mt = 0; mt < 4; mt++) { f32x4 v = {b, b, b, b}; acc[mt][nt2] = v; }
        }
#pragma unroll
        for (int kc = 0; kc < 3; kc++) {
#pragma unroll
            for (int nt2 = 0; nt2 < 2; nt2++) {
                bf16x8 bfr = Ww1F[(kc * 8 + w * 2 + nt2) * 64 + lane];
#pragma unroll
                for (int mt = 0; mt < 4; mt++)
                    acc[mt][nt2] = __builtin_amdgcn_mfma_f32_16x16x32_bf16(
                        U.XF[(kc * 4 + mt) * 64 + lane], bfr, acc[mt][nt2], 0, 0, 0);
            }
        }
        __syncthreads();

        {   // relu + transpose -> HF (aliases XF base)
            __bf16* HFp = (__bf16*)U.XF;
#pragma unroll
            for (int nt2 = 0; nt2 < 2; nt2++) {
                int cw = (w * 2 + nt2) * 16 + l16;
                int kc2 = cw >> 5, quad2 = (cw >> 3) & 3, ii = cw & 7;
#pragma unroll
                for (int mt = 0; mt < 4; mt++)
#pragma unroll
                    for (int r = 0; r < 4; r++)
                        HFp[(((kc2 * 4 + mt) * 64) + quad2 * 16 + quad * 4 + r) * 8 + ii] =
                            (__bf16)fmaxf(acc[mt][nt2][r], 0.f);
            }
        }
        __syncthreads();

        {   // GEMM2 + masked column-sum (wave w = col-tile, mh loop)
            f32x4 acc2[2][2];
            float b2 = bw2[w * 16 + l16];
#pragma unroll
            for (int mh = 0; mh < 2; mh++)
#pragma unroll
                for (int m = 0; m < 2; m++) { f32x4 v = {b2, b2, b2, b2}; acc2[mh][m] = v; }
#pragma unroll
            for (int kc = 0; kc < 4; kc++) {
                bf16x8 b2f = Ww2F[(kc * 4 + w) * 64 + lane];
#pragma unroll
                for (int mh = 0; mh < 2; mh++)
#pragma unroll
                    for (int m = 0; m < 2; m++)
                        acc2[mh][m] = __builtin_amdgcn_mfma_f32_16x16x32_bf16(
                            U.XF[(kc * 4 + mh * 2 + m) * 64 + lane], b2f, acc2[mh][m], 0, 0, 0);
            }
            float s = 0.f;
#pragma unroll
            for (int mh = 0; mh < 2; mh++)
#pragma unroll
                for (int m = 0; m < 2; m++)
#pragma unroll
                    for (int r = 0; r < 4; r++) {
                        int node = n0 + (mh * 2 + m) * 16 + quad * 4 + r;
                        s += (node < NN) ? acc2[mh][m][r] : 0.f;
                    }
            s += __shfl_xor(s, 16, 64);
            s += __shfl_xor(s, 32, 64);
            if (quad == 0) atomicAdd(m_agg_w + w * 16 + l16, s);
        }
        return;
    }

    // ================= edge path (32 edges/block, bf16 table gather) ========
    const int e0 = blockIdx.x * 32;          // NE % 32 == 0

    {   // ---- gather: 8 threads/edge, thread q loads 16B chunk q of BOTH rows
        const int ee = t >> 3, q = t & 7;    // ee 0..31
        const int mt = ee >> 4, l16e = ee & 15;
        const int eg = e0 + ee;
        const int rs = ei[eg], rt = ei[NE + eg];
        const bf16x8* zs = (const bf16x8*)((const char*)magg_rows + (long)rs * 256 + 128);
        const bf16x8* zt = (const bf16x8*)((const char*)magg_rows + (long)rt * 256 + 128);
        bf16x8 sa = zs[q];                   // src cols q*8 .. q*8+7
        bf16x8 ta = zt[q];                   // tgt cols q*8 .. q*8+7
        const int kcs = q >> 2, qslot = q & 3;
        U.XF[(kcs * 2 + mt) * 64 + qslot * 16 + l16e]       = sa;
        U.XF[((kcs + 2) * 2 + mt) * 64 + qslot * 16 + l16e] = ta;
        if (q == 4) tgt_s[ee] = rt;
        if (q == 0) {        // edge features (cols 128..135) from bf16 chunk 0
            float dx = (float)sa[0] - (float)ta[0];
            float dy = (float)sa[1] - (float)ta[1];
            float dz = (float)sa[2] - (float)ta[2];
            float ax = (float)sa[3], ay = (float)sa[4], az = (float)sa[5];
            float bx = (float)ta[3], by = (float)ta[4], bz = (float)ta[5];
            float cx = ay * bz - az * by;
            float cy = az * bx - ax * bz;
            float cz = ax * by - ay * bx;
            bf16x8 f;
            f[0] = (__bf16)dx; f[1] = (__bf16)dy; f[2] = (__bf16)dz;
            f[3] = (__bf16)(dx * dx + dy * dy + dz * dz);
            f[4] = (__bf16)cx; f[5] = (__bf16)cy; f[6] = (__bf16)cz;
            f[7] = (__bf16)sqrtf(cx * cx + cy * cy + cz * cz);
            U.XF[(8 + mt) * 64 + l16e] = f;
        } else if (q >= 5) { // zero pad (cols 136..159)
            bf16x8 z;
#pragma unroll
            for (int i = 0; i < 8; i++) z[i] = (__bf16)0.f;
            U.XF[(8 + mt) * 64 + (q - 4) * 16 + l16e] = z;
        }
    }
    __syncthreads();                         // B1: XF + tgt_s ready

    // ---- GEMM1: wave owns 4 col-tiles (msg 2w,2w+1; gate 8+2w,8+2w+1) ----
    f32x4 acc[2][4];
#pragma unroll
    for (int nt = 0; nt < 4; nt++) {
        float b = (nt < 2) ? be1[(w * 2 + nt) * 16 + l16]
                           : bg1[(w * 2 + nt - 2) * 16 + l16];
#pragma unroll
        for (int mt = 0; mt < 2; mt++) { f32x4 v = {b, b, b, b}; acc[mt][nt] = v; }
    }
#pragma unroll
    for (int kc = 0; kc < 5; kc++) {
        bf16x8 bf0 = We1F[(kc * 16 + w * 2) * 64 + lane];
        bf16x8 bf1 = We1F[(kc * 16 + w * 2 + 1) * 64 + lane];
        bf16x8 bf2 = We1F[(kc * 16 + 8 + w * 2) * 64 + lane];
        bf16x8 bf3 = We1F[(kc * 16 + 8 + w * 2 + 1) * 64 + lane];
#pragma unroll
        for (int mt = 0; mt < 2; mt++) {
            bf16x8 af = U.XF[(kc * 2 + mt) * 64 + lane];
            acc[mt][0] = __builtin_amdgcn_mfma_f32_16x16x32_bf16(af, bf0, acc[mt][0], 0, 0, 0);
            acc[mt][1] = __builtin_amdgcn_mfma_f32_16x16x32_bf16(af, bf1, acc[mt][1], 0, 0, 0);
            acc[mt][2] = __builtin_amdgcn_mfma_f32_16x16x32_bf16(af, bf2, acc[mt][2], 0, 0, 0);
            acc[mt][3] = __builtin_amdgcn_mfma_f32_16x16x32_bf16(af, bf3, acc[mt][3], 0, 0, 0);
        }
    }
    __syncthreads();                         // B2: XF reads done (HF may overwrite)

    {   // ---- all waves: relu+transpose msg tiles -> HF, gate partials ----
        __bf16* HFp = (__bf16*)U.s.HF;
#pragma unroll
        for (int nt = 0; nt < 2; nt++) {
            int cw = (w * 2 + nt) * 16 + l16;
            int kc2 = cw >> 5, quad2 = (cw >> 3) & 3, ii = cw & 7;
#pragma unroll
            for (int mt = 0; mt < 2; mt++)
#pragma unroll
                for (int r = 0; r < 4; r++)
                    HFp[(((kc2 * 2 + mt) * 64) + quad2 * 16 + quad * 4 + r) * 8 + ii] =
                        (__bf16)fmaxf(acc[mt][nt][r], 0.f);
        }
        float gp[2][4];
#pragma unroll
        for (int mt = 0; mt < 2; mt++)
#pragma unroll
            for (int r = 0; r < 4; r++) gp[mt][r] = 0.f;
#pragma unroll
        for (int nt = 2; nt < 4; nt++) {
            float wg = Wg2[(w * 2 + nt - 2) * 16 + l16];
#pragma unroll
            for (int mt = 0; mt < 2; mt++)
#pragma unroll
                for (int r = 0; r < 4; r++)
                    gp[mt][r] += fmaxf(acc[mt][nt][r], 0.f) * wg;
        }
#pragma unroll
        for (int mask = 1; mask < 16; mask <<= 1)
#pragma unroll
            for (int mt = 0; mt < 2; mt++)
#pragma unroll
                for (int r = 0; r < 4; r++)
                    gp[mt][r] += __shfl_xor(gp[mt][r], mask, 64);
        if (l16 == 0) {
#pragma unroll
            for (int mt = 0; mt < 2; mt++)
#pragma unroll
                for (int r = 0; r < 4; r++)
                    gred[w][mt * 16 + quad * 4 + r] = gp[mt][r];
        }
    }
    __syncthreads();                         // B3: HF + gred ready

    {   // ---- GEMM2 (all 4 waves, col-tile w) + sigmoid + M pack ----
        f32x4 acc2[2];
        float b2 = be2[w * 16 + l16];
#pragma unroll
        for (int mt = 0; mt < 2; mt++) { f32x4 v = {b2, b2, b2, b2}; acc2[mt] = v; }
#pragma unroll
        for (int kc = 0; kc < 4; kc++) {
            bf16x8 c2 = We2F[(kc * 4 + w) * 64 + lane];
#pragma unroll
            for (int mt = 0; mt < 2; mt++)
                acc2[mt] = __builtin_amdgcn_mfma_f32_16x16x32_bf16(
                    U.s.HF[(kc * 2 + mt) * 64 + lane], c2, acc2[mt], 0, 0, 0);
        }

        // redundant per-lane sigmoid from gred (lanes 32-63 mirror 0-31)
        float wgtreg;
        {
            int e = lane & 31;
            float g = bg2[0] + gred[0][e] + gred[1][e] + gred[2][e] + gred[3][e];
            wgtreg = 1.f / (1.f + __expf(-g));
        }

#pragma unroll
        for (int mt = 0; mt < 2; mt++)
#pragma unroll
            for (int r = 0; r < 4; r++) {
                int edge = mt * 16 + quad * 4 + r;
                float wg = __shfl(wgtreg, edge, 64);
                U.s.M[edge * 68 + w * 16 + l16] =
                    (_Float16)(acc2[mt][r] * wg);
            }
    }
    __syncthreads();                         // B4: M ready

    // ---- scatter: all 4 waves, packed v2f16 atomics ----
    // thread t, step k: edge = (t>>5) + 8k, pair p = t&31.
    // per wave-instr: 2 rows x 128 B = 4 cachelines x 16 lanes.
    {
        const int p = t & 31, eh = t >> 5;
        char* base = (char*)magg_rows;
#pragma unroll
        for (int k = 0; k < 4; k++) {
            int e = eh + k * 8;
            f16x2 v = *(const f16x2*)&U.s.M[e * 68 + p * 2];
            pk_atomic_add_f16(base + (long)tgt_s[e] * 256 + p * 4, v);
        }
    }
}

// ---------------- node kernel: 512 thr, 2 barriers (separate XF/HF) --------
__global__ __launch_bounds__(512, 4) void node_kernel(
    const float* __restrict__ m_agg_w,
    const bf16x8* __restrict__ Wn1F, const bf16x8* __restrict__ Wn2F,
    const float* __restrict__ bn1, const float* __restrict__ bn2,
    float* __restrict__ outp)     // rows: f16 acc | bf16 z, then output
{
    __shared__ bf16x8 XF[1024];   // 16 KB
    __shared__ bf16x8 HF[1024];   // 16 KB (separate -> no XF/HF hazard barrier)
    const int t = threadIdx.x;
    const int n0 = blockIdx.x * 64;
    const int lane = t & 63, w = t >> 6;
    const int quad = lane >> 4, l16 = lane & 15;

    {   // gather: 8 threads/node; halves: z-bf16 | m_agg(f16) + m_agg_w
        int nn = t >> 3, q = t & 7;
        int mt = nn >> 4, l16e = nn & 15;
        int node = n0 + nn; if (node >= NN) node = NN - 1;
        int half = q >> 2, sub = q & 3;
        bf16x8 c0, c1;
        if (half == 0) {
            const bf16x8* zr = (const bf16x8*)((const char*)outp + (long)node * 256 + 128) + sub * 2;
            c0 = zr[0]; c1 = zr[1];
        } else {
            const f16x8* mr = (const f16x8*)((const char*)outp + (long)node * 256) + sub * 2;
            f16x8 r0 = mr[0], r1 = mr[1];
            const float* mw = m_agg_w + sub * 16;
#pragma unroll
            for (int i = 0; i < 8; i++) {
                c0[i] = (__bf16)((float)r0[i] + mw[i]);
                c1[i] = (__bf16)((float)r1[i] + mw[i + 8]);
            }
        }
        int kcs = (sub >> 1) + half * 2, qa = (sub & 1) * 2;
        XF[(kcs * 4 + mt) * 64 + qa * 16 + l16e]       = c0;
        XF[(kcs * 4 + mt) * 64 + (qa + 1) * 16 + l16e] = c1;
    }
    __syncthreads();                         // B1: XF ready

    f32x4 acc[4];
    {
        float b = bn1[w * 16 + l16];
#pragma unroll
        for (int mt = 0; mt < 4; mt++) { f32x4 v = {b, b, b, b}; acc[mt] = v; }
    }
#pragma unroll
    for (int kc = 0; kc < 4; kc++) {
        bf16x8 bfr = Wn1F[(kc * 8 + w) * 64 + lane];
#pragma unroll
        for (int mt = 0; mt < 4; mt++)
            acc[mt] = __builtin_amdgcn_mfma_f32_16x16x32_bf16(
                XF[(kc * 4 + mt) * 64 + lane], bfr, acc[mt], 0, 0, 0);
    }

    {   // relu + transpose -> HF (separate buffer: no barrier needed)
        __bf16* HFp = (__bf16*)HF;
        int cw = w * 16 + l16;
        int kc2 = cw >> 5, quad2 = (cw >> 3) & 3, ii = cw & 7;
#pragma unroll
        for (int mt = 0; mt < 4; mt++)
#pragma unroll
            for (int r = 0; r < 4; r++)
                HFp[(((kc2 * 4 + mt) * 64) + quad2 * 16 + quad * 4 + r) * 8 + ii] =
                    (__bf16)fmaxf(acc[mt][r], 0.f);
    }
    __syncthreads();                         // B2: HF ready

    {   // GEMM2 + store: nt = w&3, m-half mh = w>>2
        const int nt = w & 3, mh = w >> 2;
        f32x4 acc2[2];
        float b2 = bn2[nt * 16 + l16];
#pragma unroll
        for (int m = 0; m < 2; m++) { f32x4 v = {b2, b2, b2, b2}; acc2[m] = v; }
#pragma unroll
        for (int kc = 0; kc < 4; kc++) {
            bf16x8 b2f = Wn2F[(kc * 4 + nt) * 64 + lane];
#pragma unroll
            for (int m = 0; m < 2; m++)
                acc2[m] = __builtin_amdgcn_mfma_f32_16x16x32_bf16(
                    HF[(kc * 4 + mh * 2 + m) * 64 + lane], b2f, acc2[m], 0, 0, 0);
        }
#pragma unroll
        for (int m = 0; m < 2; m++)
#pragma unroll
            for (int r = 0; r < 4; r++) {
                int node = n0 + (mh * 2 + m) * 16 + quad * 4 + r;
                if (node < NN)
                    outp[(long)node * 64 + nt * 16 + l16] = acc2[m][r];
            }
    }
}

extern "C" void kernel_launch(void* const* d_in, const int* in_sizes, int n_in,
                              void* d_out, int out_size, void* d_ws, size_t ws_size,
                              hipStream_t stream)
{
    const float* z_h       = (const float*)d_in[0];
    const float* pos_world = (const float*)d_in[1];
    const int*   ei        = (const int*)d_in[2];
    const float* We1 = (const float*)d_in[3];  const float* be1 = (const float*)d_in[4];
    const float* We2 = (const float*)d_in[5];  const float* be2 = (const float*)d_in[6];
    const float* Wg1 = (const float*)d_in[7];  const float* bg1 = (const float*)d_in[8];
    const float* Wg2 = (const float*)d_in[9];  const float* bg2 = (const float*)d_in[10];
    const float* Wn1 = (const float*)d_in[11]; const float* bn1 = (const float*)d_in[12];
    const float* Wn2 = (const float*)d_in[13]; const float* bn2 = (const float*)d_in[14];
    const float* Ww1 = (const float*)d_in[15]; const float* bw1 = (const float*)d_in[16];
    const float* Ww2 = (const float*)d_in[17]; const float* bw2 = (const float*)d_in[18];

    float*  outp    = (float*)d_out;
    float*  m_agg_w = (float*)d_ws;         // 64 floats
    bf16x8* wsF     = (bf16x8*)((char*)d_ws + 256);

    prep<<<(NN * 8 + 255) / 256, 256, 0, stream>>>(
        We1, Wg1, We2, Wn1, Wn2, Ww1, Ww2, wsF, z_h, outp, m_agg_w);
    fused_kernel<<<EBLOCKS + WBLOCKS, 256, 0, stream>>>(
        z_h, ei, wsF + WE1F_OFF, wsF + WE2F_OFF,
        be1, be2, bg1, Wg2, bg2,
        pos_world, wsF + WW1F_OFF, wsF + WW2F_OFF, bw1, bw2,
        outp, m_agg_w);
    node_kernel<<<(NN + 63) / 64, 512, 0, stream>>>(
        m_agg_w, wsF + WN1F_OFF, wsF + WN2F_OFF, bn1, bn2, outp);
}